// Round 11
// baseline (251.802 us; speedup 1.0000x reference)
//
#include <hip/hip_runtime.h>
#include <math.h>

#define NE   2048
#define FEAT 512

typedef short short8 __attribute__((ext_vector_type(8)));
typedef float f32x4  __attribute__((ext_vector_type(4)));

__device__ __forceinline__ unsigned short f2bf(float f) {
    union { float f; unsigned u; } v; v.f = f;
    unsigned r = v.u + 0x7fffu + ((v.u >> 16) & 1u);   // RNE
    return (unsigned short)(r >> 16);
}
__device__ __forceinline__ float bf2f(unsigned b) {
    union { unsigned u; float f; } v; v.u = b << 16;
    return v.f;
}
__device__ __forceinline__ unsigned pack2(float a, float b) {
    return (unsigned)f2bf(a) | ((unsigned)f2bf(b) << 16);
}

// async global->LDS, 16B per lane; lds base wave-uniform, HW deposits lane i at +i*16.
__device__ __forceinline__ void gld16(unsigned short* lds, const unsigned short* g) {
    __builtin_amdgcn_global_load_lds(
        (const __attribute__((address_space(1))) unsigned int*)g,
        (__attribute__((address_space(3))) unsigned int*)lds,
        16, 0, 0);
}

// raw barrier (no implicit vmcnt drain)
__device__ __forceinline__ void bar() {
    asm volatile("" ::: "memory");
    __builtin_amdgcn_s_barrier();
    asm volatile("" ::: "memory");
}
#define VMW(n) asm volatile("s_waitcnt vmcnt(" #n ")" ::: "memory")

// T2 swizzle pair (rule #21): linear LDS dest + inverse-swizzled global source +
// swizzled read. 128B rows: blk^=(row&7); 256B rows: blk^=(row&15).

// ---------------------------------------------------------------------------
// K0: merged prep. Blocks 0..2047: x[n][f][r] fp32 -> xt[(n*8+r)][f] bf16.
// Blocks 2048..2431: W fp32 -> bf16 (3 x 512x512).
// ---------------------------------------------------------------------------
__global__ __launch_bounds__(256) void prep_kernel(
    const float* __restrict__ x,
    const float* __restrict__ Wq, const float* __restrict__ Wk, const float* __restrict__ Wd,
    unsigned short* __restrict__ xt, unsigned short* __restrict__ wbf)
{
    __shared__ float xs[8 * 516];
    const int t = threadIdx.x;
    const int bid = blockIdx.x;
    if (bid < 2048) {
        const int n = bid;
        const float4* xp = (const float4*)(x + (size_t)n * 4096);
        #pragma unroll
        for (int i = 0; i < 4; ++i) {
            int idx = t + 256 * i;
            float4 v = xp[idx];
            int f = idx >> 1, rh = (idx & 1) * 4;
            xs[(rh + 0) * 516 + f] = v.x;
            xs[(rh + 1) * 516 + f] = v.y;
            xs[(rh + 2) * 516 + f] = v.z;
            xs[(rh + 3) * 516 + f] = v.w;
        }
        __syncthreads();
        const int r = t >> 5, f0 = (t & 31) * 16;
        const float* src = &xs[r * 516 + f0];
        unsigned o[8];
        #pragma unroll
        for (int j = 0; j < 8; ++j) o[j] = pack2(src[2 * j], src[2 * j + 1]);
        unsigned short* dst = xt + (size_t)n * 4096 + r * 512 + f0;
        *(uint4*)dst       = make_uint4(o[0], o[1], o[2], o[3]);
        *(uint4*)(dst + 8) = make_uint4(o[4], o[5], o[6], o[7]);
    } else {
        const int b = bid - 2048;
        const int wy = b >> 7, wx = b & 127;
        const float* W = (wy == 0) ? Wq : (wy == 1) ? Wk : Wd;
        unsigned short* o = wbf + (size_t)wy * 262144;
        const int idx = wx * 2048 + t * 8;
        const float4* p = (const float4*)(W + idx);
        float4 v0 = p[0], v1 = p[1];
        *(uint4*)(o + idx) = make_uint4(pack2(v0.x, v0.y), pack2(v0.z, v0.w),
                                        pack2(v1.x, v1.y), pack2(v1.z, v1.w));
    }
}

// ---------------------------------------------------------------------------
// K1: proj GEMM. NEW (r10-score transplant): single-buffer 2-phase,
// __launch_bounds__(512,2) -> 2 blocks/CU (LDS 69.6KB incl. epilogue-T).
// 256M x 128N, BK=64, 8 waves = 4M x 2N, T2 swizzle, fused s2 partial,
// LDS-transpose coalesced epilogue. Grid 768 -> 1.5 rounds at 2/CU.
// ---------------------------------------------------------------------------
__global__ __launch_bounds__(512, 2) void proj_gemm(
    const unsigned short* __restrict__ wbf, const unsigned short* __restrict__ xt,
    unsigned short* __restrict__ qb, unsigned short* __restrict__ kb, unsigned short* __restrict__ db,
    float* __restrict__ s2)
{
    __shared__ unsigned short SM[34816];   // A[16384] | B[8192] staging; T[256*136] epilogue
    const int t = threadIdx.x;
    int bid = blockIdx.x + 128 * (blockIdx.y + 2 * blockIdx.z);
    int swz = (bid & 7) * 96 + (bid >> 3);
    const int bx = swz & 127, rest = swz >> 7;
    const int my = rest & 1, w = rest >> 1;
    const unsigned short* W = wbf + (size_t)w * 262144;
    unsigned short* out = (w == 0) ? qb : (w == 1) ? kb : db;
    const int M0 = my * 256;
    const int N0 = bx * 128;
    const int wave = t >> 6, lane = t & 63, quad = lane >> 4, l16 = lane & 15;
    const int wr = wave >> 1, wc = wave & 1;       // 4M x 2N wave grid
    const int lrow = lane >> 3;
    const int scol = ((lane & 7) ^ lrow) * 8;
    unsigned short* A = SM;
    unsigned short* B = SM + 16384;

    f32x4 acc[4][4];
    #pragma unroll
    for (int m = 0; m < 4; ++m)
        #pragma unroll
        for (int n = 0; n < 4; ++n) acc[m][n] = {0.f, 0.f, 0.f, 0.f};

    for (int kc = 0; kc < 8; ++kc) {
        #pragma unroll
        for (int p = 0; p < 4; ++p) {
            int c = p * 8 + wave;
            gld16(A + c * 512, W + (size_t)(M0 + c * 8 + lrow) * 512 + kc * 64 + scol);
        }
        #pragma unroll
        for (int p = 0; p < 2; ++p) {
            int c = p * 8 + wave;
            gld16(B + c * 512, xt + (size_t)(N0 + c * 8 + lrow) * 512 + kc * 64 + scol);
        }
        __syncthreads();
        #pragma unroll
        for (int kk = 0; kk < 2; ++kk) {
            int so = ((kk * 4 + quad) ^ (l16 & 7)) * 8;
            short8 a[4], b[4];
            #pragma unroll
            for (int m = 0; m < 4; ++m)
                a[m] = *(const short8*)&A[(wr * 64 + m * 16 + l16) * 64 + so];
            #pragma unroll
            for (int n = 0; n < 4; ++n)
                b[n] = *(const short8*)&B[(wc * 64 + n * 16 + l16) * 64 + so];
            #pragma unroll
            for (int m = 0; m < 4; ++m)
                #pragma unroll
                for (int n = 0; n < 4; ++n)
                    acc[m][n] = __builtin_amdgcn_mfma_f32_16x16x32_bf16(a[m], b[n], acc[m][n], 0, 0, 0);
        }
        __syncthreads();
    }

    // fused scales partial: sum over rows of y^2 per electron column
    float cs[4];
    #pragma unroll
    for (int n = 0; n < 4; ++n) {
        float s = 0.f;
        #pragma unroll
        for (int m = 0; m < 4; ++m)
            #pragma unroll
            for (int reg = 0; reg < 4; ++reg)
                s += acc[m][n][reg] * acc[m][n][reg];
        cs[n] = s;
    }
    #pragma unroll
    for (int n = 0; n < 4; ++n) {
        float s = cs[n];
        s += __shfl_xor(s, 16);
        s += __shfl_xor(s, 32);
        s += __shfl_xor(s, 1);
        s += __shfl_xor(s, 2);
        s += __shfl_xor(s, 4);
        if ((lane & 7) == 0 && lane < 16) {
            int n_elec = (N0 >> 3) + wc * 8 + n * 2 + (lane >> 3);
            atomicAdd(&s2[w * NE + n_elec], s);
        }
    }

    // epilogue: acc -> padded LDS bf16 tile (256 x 136) -> 16B stores
    unsigned short* T = SM;
    #pragma unroll
    for (int m = 0; m < 4; ++m)
        #pragma unroll
        for (int reg = 0; reg < 4; ++reg) {
            int row = wr * 64 + m * 16 + quad * 4 + reg;
            #pragma unroll
            for (int n = 0; n < 4; ++n)
                T[row * 136 + wc * 64 + n * 16 + l16] = f2bf(acc[m][n][reg]);
        }
    __syncthreads();
    #pragma unroll
    for (int i = 0; i < 8; ++i) {
        int c = t + 512 * i;
        int row = c & 255, cb = c >> 8;
        uint4 v = *(const uint4*)(T + row * 136 + cb * 8);
        int hl = M0 + row;
        unsigned short* dst = out + (size_t)(hl >> 6) * 1048576 + (size_t)(hl & 63) * 8
                                  + (size_t)((N0 >> 3) + cb) * 512;
        *(uint4*)dst = v;
    }
}

// ---------------------------------------------------------------------------
// K1.5: dT[h][f][n] = db[h][n][f] * rsqrt(s2d[n])
// ---------------------------------------------------------------------------
__global__ __launch_bounds__(256) void dtrans_kernel(
    const unsigned short* __restrict__ db, const float* __restrict__ s2d,
    unsigned short* __restrict__ dT)
{
    __shared__ float Ts[64 * 68];
    const int t = threadIdx.x;
    const int h = blockIdx.z, n0 = blockIdx.y * 64, f0 = blockIdx.x * 64;
    const int rr = t >> 3, cs = (t & 7) * 8;
    #pragma unroll
    for (int p = 0; p < 2; ++p) {
        int row = rr + p * 32;
        float sc = rsqrtf(s2d[n0 + row]);
        uint4 v = *(const uint4*)(db + ((size_t)h * NE + n0 + row) * 512 + f0 + cs);
        unsigned a[4] = {v.x, v.y, v.z, v.w};
        float* d = &Ts[row * 68 + cs];
        #pragma unroll
        for (int j = 0; j < 4; ++j) {
            d[2 * j]     = bf2f(a[j] & 0xffffu) * sc;
            d[2 * j + 1] = bf2f(a[j] >> 16) * sc;
        }
    }
    __syncthreads();
    const int f = t >> 2, ns = (t & 3) * 16;
    unsigned o[8];
    #pragma unroll
    for (int j = 0; j < 8; ++j)
        o[j] = pack2(Ts[(ns + 2 * j) * 68 + f], Ts[(ns + 2 * j + 1) * 68 + f]);
    unsigned short* dst = dT + ((size_t)h * 512 + f0 + f) * NE + n0 + ns;
    *(uint4*)dst       = make_uint4(o[0], o[1], o[2], o[3]);
    *(uint4*)(dst + 8) = make_uint4(o[4], o[5], o[6], o[7]);
}

// ---------------------------------------------------------------------------
// K2a: P[hg][n][m] = exp((q.k)*rsq(s2q[n])*rsq(s2k[m])) bf16 (frozen r10 form):
// single-buffer 2-phase, (512,2) -> 2 blocks/CU, grid 512 all-resident.
// 256n x 128m, 4n x 2m waves, T2 swizzle, XCD swizzle, coalesced P stores.
// ---------------------------------------------------------------------------
__global__ __launch_bounds__(512, 2) void score_kernel(
    const unsigned short* __restrict__ qb, const unsigned short* __restrict__ kb,
    const float* __restrict__ s2, unsigned short* __restrict__ P,
    float* __restrict__ sums, int g)
{
    __shared__ unsigned short SM[34816];   // A[16384] | B[8192] staging; T[256*136] epilogue
    const int t = threadIdx.x;
    int bid = blockIdx.x + 16 * (blockIdx.y + 8 * blockIdx.z);
    int swz = (bid & 7) * 64 + (bid >> 3);
    const int bx = swz & 15, by = (swz >> 4) & 7, bz = swz >> 7;
    const int hg = bz, h = g * 4 + hg;
    const int n0 = by * 256, m0 = bx * 128;
    const int wave = t >> 6, lane = t & 63, quad = lane >> 4, l16 = lane & 15;
    const int wr = wave >> 1, wc = wave & 1;       // 4n x 2m wave grid
    const int lrow = lane >> 3;
    const int scol = ((lane & 7) ^ lrow) * 8;
    const unsigned short* qh = qb + (size_t)h * NE * 512;
    const unsigned short* kh = kb + (size_t)h * NE * 512;
    unsigned short* A = SM;
    unsigned short* B = SM + 16384;

    f32x4 acc[4][4];
    #pragma unroll
    for (int m = 0; m < 4; ++m)
        #pragma unroll
        for (int n = 0; n < 4; ++n) acc[m][n] = {0.f, 0.f, 0.f, 0.f};

    for (int kc = 0; kc < 8; ++kc) {
        #pragma unroll
        for (int p = 0; p < 4; ++p) {
            int c = p * 8 + wave;
            gld16(A + c * 512, qh + (size_t)(n0 + c * 8 + lrow) * 512 + kc * 64 + scol);
        }
        #pragma unroll
        for (int p = 0; p < 2; ++p) {
            int c = p * 8 + wave;
            gld16(B + c * 512, kh + (size_t)(m0 + c * 8 + lrow) * 512 + kc * 64 + scol);
        }
        __syncthreads();
        #pragma unroll
        for (int kk = 0; kk < 2; ++kk) {
            int so = ((kk * 4 + quad) ^ (l16 & 7)) * 8;
            short8 a[4], b[4];
            #pragma unroll
            for (int m = 0; m < 4; ++m)
                a[m] = *(const short8*)&A[(wr * 64 + m * 16 + l16) * 64 + so];
            #pragma unroll
            for (int n = 0; n < 4; ++n)
                b[n] = *(const short8*)&B[(wc * 64 + n * 16 + l16) * 64 + so];
            #pragma unroll
            for (int m = 0; m < 4; ++m)
                #pragma unroll
                for (int n = 0; n < 4; ++n)
                    acc[m][n] = __builtin_amdgcn_mfma_f32_16x16x32_bf16(a[m], b[n], acc[m][n], 0, 0, 0);
        }
        __syncthreads();
    }

    float ik[4];
    #pragma unroll
    for (int n = 0; n < 4; ++n) ik[n] = rsqrtf(s2[NE + m0 + wc * 64 + n * 16 + l16]);

    unsigned short* T = SM;                        // 256*136 shorts = 69.6 KB
    #pragma unroll
    for (int m = 0; m < 4; ++m)
        #pragma unroll
        for (int reg = 0; reg < 4; ++reg) {
            int row = wr * 64 + m * 16 + quad * 4 + reg;
            float qs = rsqrtf(s2[n0 + row]);
            float rs = 0.f;
            #pragma unroll
            for (int n = 0; n < 4; ++n) {
                float e = __expf(acc[m][n][reg] * qs * ik[n]);
                unsigned short bx16 = f2bf(e);
                T[row * 136 + wc * 64 + n * 16 + l16] = bx16;
                rs += bf2f(bx16);
            }
            rs += __shfl_xor(rs, 1);
            rs += __shfl_xor(rs, 2);
            rs += __shfl_xor(rs, 4);
            rs += __shfl_xor(rs, 8);
            if (l16 == 0) atomicAdd(&sums[hg * NE + n0 + row], rs);
        }
    __syncthreads();
    unsigned short* Ph = P + (size_t)hg * NE * NE;
    #pragma unroll
    for (int i = 0; i < 8; ++i) {
        int c = t + 512 * i;
        int row = c >> 4, cb = c & 15;
        uint4 v = *(const uint4*)(T + row * 136 + cb * 8);
        *(uint4*)(Ph + (size_t)(n0 + row) * NE + m0 + cb * 8) = v;
    }
}

// ---------------------------------------------------------------------------
// K2b: V[n][f] = (sum_m P[n][m]*dT[f][m]) / sums[n]  (frozen r9 form)
// BK=128, 512 thr, 128n x 128f, counted-vmcnt(8) 2-deep dbuf (128 KB LDS),
// T2 swizzle over 16-block rows, XCD swizzle.
// ---------------------------------------------------------------------------
__global__ __launch_bounds__(512, 1) void combine_kernel(
    const unsigned short* __restrict__ P, const unsigned short* __restrict__ dT,
    const float* __restrict__ sums, float* __restrict__ out, int g)
{
    __shared__ unsigned short Ps[2][16384];
    __shared__ unsigned short Ds[2][16384];
    const int t = threadIdx.x;
    int bid = blockIdx.x + 4 * (blockIdx.y + 16 * blockIdx.z);
    int swz = (bid & 7) * 32 + (bid >> 3);
    const int bx = swz & 3, by = (swz >> 2) & 15, bz = swz >> 6;
    const int hg = bz, h = g * 4 + hg;
    const int n0 = by * 128, f0 = bx * 128;
    const int wave = t >> 6, lane = t & 63, quad = lane >> 4, l16 = lane & 15;
    const int wn = wave >> 1, wf = wave & 1;
    const int lrow4 = lane >> 4;
    const unsigned short* Ph = P + (size_t)hg * NE * NE;
    const unsigned short* dh = dT + (size_t)h * 512 * NE;

    f32x4 acc[2][4];
    #pragma unroll
    for (int i = 0; i < 2; ++i)
        #pragma unroll
        for (int j = 0; j < 4; ++j) acc[i][j] = {0.f, 0.f, 0.f, 0.f};

    auto STAGE = [&](int mc, int buf) {
        #pragma unroll
        for (int p = 0; p < 4; ++p) {
            int c = p * 8 + wave;
            int row = c * 4 + lrow4;
            int sb = ((lane & 15) ^ (row & 15)) * 8;
            gld16(&Ps[buf][c * 512], Ph + (size_t)(n0 + row) * NE + mc * 128 + sb);
        }
        #pragma unroll
        for (int p = 0; p < 4; ++p) {
            int c = p * 8 + wave;
            int row = c * 4 + lrow4;
            int sb = ((lane & 15) ^ (row & 15)) * 8;
            gld16(&Ds[buf][c * 512], dh + (size_t)(f0 + row) * NE + mc * 128 + sb);
        }
    };
    auto COMPUTE = [&](int buf) {
        #pragma unroll
        for (int kk = 0; kk < 4; ++kk) {
            int so = ((kk * 4 + quad) ^ l16) * 8;
            short8 a0 = *(const short8*)&Ps[buf][(wn * 32 + l16) * 128 + so];
            short8 a1 = *(const short8*)&Ps[buf][(wn * 32 + 16 + l16) * 128 + so];
            #pragma unroll
            for (int ct = 0; ct < 4; ++ct) {
                short8 bb = *(const short8*)&Ds[buf][(wf * 64 + ct * 16 + l16) * 128 + so];
                acc[0][ct] = __builtin_amdgcn_mfma_f32_16x16x32_bf16(a0, bb, acc[0][ct], 0, 0, 0);
                acc[1][ct] = __builtin_amdgcn_mfma_f32_16x16x32_bf16(a1, bb, acc[1][ct], 0, 0, 0);
            }
        }
    };

    STAGE(0, 0);
    STAGE(1, 1);
    for (int mc = 0; mc < 16; ++mc) {
        if (mc < 15) { VMW(8); } else { VMW(0); }
        bar();
        COMPUTE(mc & 1);
        bar();
        if (mc + 2 < 16) STAGE(mc + 2, mc & 1);
    }

    #pragma unroll
    for (int rt = 0; rt < 2; ++rt)
        #pragma unroll
        for (int reg = 0; reg < 4; ++reg) {
            int nl = wn * 32 + rt * 16 + quad * 4 + reg;
            float li = 1.0f / sums[hg * NE + n0 + nl];
            float* orow = out + (size_t)(n0 + nl) * 4096 + h * 512 + f0 + wf * 64;
            #pragma unroll
            for (int ct = 0; ct < 4; ++ct)
                orow[ct * 16 + l16] = acc[rt][ct][reg] * li;
        }
}

extern "C" void kernel_launch(void* const* d_in, const int* in_sizes, int n_in,
                              void* d_out, int out_size, void* d_ws, size_t ws_size,
                              hipStream_t stream)
{
    const float* x  = (const float*)d_in[0];
    const float* Qw = (const float*)d_in[1];
    const float* Kw = (const float*)d_in[2];
    const float* Dw = (const float*)d_in[3];
    float* out = (float*)d_out;

    char* ws = (char*)d_ws;
    unsigned short* xt = (unsigned short*)ws;                          // 16 MB
    unsigned short* db = (unsigned short*)(ws + 16777216);             // 16 MB
    unsigned short* P  = (unsigned short*)ws;                          // 32 MB (reuse)
    unsigned short* qb = (unsigned short*)(ws + 33554432);             // 16 MB
    unsigned short* kb = (unsigned short*)(ws + 33554432 + 16777216);  // 16 MB
    unsigned short* dT = (unsigned short*)(ws + 33554432 + 2 * 16777216); // 16 MB
    unsigned short* wbf = dT;                                          // 1.5 MB (reuse)
    float* sums   = (float*)(ws + 83886080);                           // 64 KB (both g)
    float* s2     = (float*)(ws + 83886080 + 65536);                   // 24 KB

    // one memset covers sums[2][4][NE] + s2[3][NE]
    hipMemsetAsync(sums, 0, 65536 + 24576, stream);
    prep_kernel<<<2432, 256, 0, stream>>>(x, Qw, Kw, Dw, xt, wbf);
    proj_gemm<<<dim3(128, 2, 3), 512, 0, stream>>>(wbf, xt, qb, kb, db, s2);
    dtrans_kernel<<<dim3(8, 32, 8), 256, 0, stream>>>(db, s2 + 2 * NE, dT);
    for (int g = 0; g < 2; ++g) {
        float* sums_g = sums + g * 4 * NE;
        score_kernel<<<dim3(16, 8, 4), 512, 0, stream>>>(qb, kb, s2, P, sums_g, g);
        combine_kernel<<<dim3(4, 16, 4), 512, 0, stream>>>(P, dT, sums_g, out, g);
    }
}

// Round 12
// 235.793 us; speedup vs baseline: 1.0679x; 1.0679x over previous
//
#include <hip/hip_runtime.h>
#include <math.h>

#define NE   2048
#define FEAT 512

typedef short short8 __attribute__((ext_vector_type(8)));
typedef float f32x4  __attribute__((ext_vector_type(4)));

__device__ __forceinline__ unsigned short f2bf(float f) {
    union { float f; unsigned u; } v; v.f = f;
    unsigned r = v.u + 0x7fffu + ((v.u >> 16) & 1u);   // RNE
    return (unsigned short)(r >> 16);
}
__device__ __forceinline__ float bf2f(unsigned b) {
    union { unsigned u; float f; } v; v.u = b << 16;
    return v.f;
}
__device__ __forceinline__ unsigned pack2(float a, float b) {
    return (unsigned)f2bf(a) | ((unsigned)f2bf(b) << 16);
}

// async global->LDS, 16B per lane; lds base wave-uniform, HW deposits lane i at +i*16.
__device__ __forceinline__ void gld16(unsigned short* lds, const unsigned short* g) {
    __builtin_amdgcn_global_load_lds(
        (const __attribute__((address_space(1))) unsigned int*)g,
        (__attribute__((address_space(3))) unsigned int*)lds,
        16, 0, 0);
}

// raw barrier (no implicit vmcnt drain)
__device__ __forceinline__ void bar() {
    asm volatile("" ::: "memory");
    __builtin_amdgcn_s_barrier();
    asm volatile("" ::: "memory");
}
#define VMW(n) asm volatile("s_waitcnt vmcnt(" #n ")" ::: "memory")

// T2 swizzle pair (rule #21): linear LDS dest + inverse-swizzled global source +
// swizzled read. 128B rows: blk^=(row&7); 256B rows: blk^=(row&15).

// ---------------------------------------------------------------------------
// K0: merged prep. Blocks 0..2047: x[n][f][r] fp32 -> xt[(n*8+r)][f] bf16.
// Blocks 2048..2431: W fp32 -> bf16 (3 x 512x512).
// ---------------------------------------------------------------------------
__global__ __launch_bounds__(256) void prep_kernel(
    const float* __restrict__ x,
    const float* __restrict__ Wq, const float* __restrict__ Wk, const float* __restrict__ Wd,
    unsigned short* __restrict__ xt, unsigned short* __restrict__ wbf)
{
    __shared__ float xs[8 * 516];
    const int t = threadIdx.x;
    const int bid = blockIdx.x;
    if (bid < 2048) {
        const int n = bid;
        const float4* xp = (const float4*)(x + (size_t)n * 4096);
        #pragma unroll
        for (int i = 0; i < 4; ++i) {
            int idx = t + 256 * i;
            float4 v = xp[idx];
            int f = idx >> 1, rh = (idx & 1) * 4;
            xs[(rh + 0) * 516 + f] = v.x;
            xs[(rh + 1) * 516 + f] = v.y;
            xs[(rh + 2) * 516 + f] = v.z;
            xs[(rh + 3) * 516 + f] = v.w;
        }
        __syncthreads();
        const int r = t >> 5, f0 = (t & 31) * 16;
        const float* src = &xs[r * 516 + f0];
        unsigned o[8];
        #pragma unroll
        for (int j = 0; j < 8; ++j) o[j] = pack2(src[2 * j], src[2 * j + 1]);
        unsigned short* dst = xt + (size_t)n * 4096 + r * 512 + f0;
        *(uint4*)dst       = make_uint4(o[0], o[1], o[2], o[3]);
        *(uint4*)(dst + 8) = make_uint4(o[4], o[5], o[6], o[7]);
    } else {
        const int b = bid - 2048;
        const int wy = b >> 7, wx = b & 127;
        const float* W = (wy == 0) ? Wq : (wy == 1) ? Wk : Wd;
        unsigned short* o = wbf + (size_t)wy * 262144;
        const int idx = wx * 2048 + t * 8;
        const float4* p = (const float4*)(W + idx);
        float4 v0 = p[0], v1 = p[1];
        *(uint4*)(o + idx) = make_uint4(pack2(v0.x, v0.y), pack2(v0.z, v0.w),
                                        pack2(v1.x, v1.y), pack2(v1.z, v1.w));
    }
}

// ---------------------------------------------------------------------------
// K1: proj GEMM (REVERTED to r10 measured-best, 42us): 256M x 128N, BK=64,
// 512 thr (8 waves = 4M x 2N), counted-vmcnt(6) 2-deep dbuf (96 KB LDS),
// T2 swizzle, fused s2 partial, LDS-transpose coalesced epilogue.
// ---------------------------------------------------------------------------
__global__ __launch_bounds__(512, 1) void proj_gemm(
    const unsigned short* __restrict__ wbf, const unsigned short* __restrict__ xt,
    unsigned short* __restrict__ qb, unsigned short* __restrict__ kb, unsigned short* __restrict__ db,
    float* __restrict__ s2)
{
    __shared__ unsigned short SM[49152];   // 96 KB: A[2][16384] | B[2][8192] shorts
    const int t = threadIdx.x;
    int bid = blockIdx.x + 128 * (blockIdx.y + 2 * blockIdx.z);
    int swz = (bid & 7) * 96 + (bid >> 3);
    const int bx = swz & 127, rest = swz >> 7;
    const int my = rest & 1, w = rest >> 1;
    const unsigned short* W = wbf + (size_t)w * 262144;
    unsigned short* out = (w == 0) ? qb : (w == 1) ? kb : db;
    const int M0 = my * 256;
    const int N0 = bx * 128;
    const int wave = t >> 6, lane = t & 63, quad = lane >> 4, l16 = lane & 15;
    const int wr = wave >> 1, wc = wave & 1;       // 4M x 2N wave grid
    const int lrow = lane >> 3;
    const int scol = ((lane & 7) ^ lrow) * 8;

    f32x4 acc[4][4];
    #pragma unroll
    for (int m = 0; m < 4; ++m)
        #pragma unroll
        for (int n = 0; n < 4; ++n) acc[m][n] = {0.f, 0.f, 0.f, 0.f};

    auto STAGE = [&](int kc, int buf) {
        unsigned short* A = SM + buf * 16384;
        unsigned short* B = SM + 32768 + buf * 8192;
        #pragma unroll
        for (int p = 0; p < 4; ++p) {
            int c = p * 8 + wave;
            gld16(A + c * 512, W + (size_t)(M0 + c * 8 + lrow) * 512 + kc * 64 + scol);
        }
        #pragma unroll
        for (int p = 0; p < 2; ++p) {
            int c = p * 8 + wave;
            gld16(B + c * 512, xt + (size_t)(N0 + c * 8 + lrow) * 512 + kc * 64 + scol);
        }
    };
    auto COMPUTE = [&](int buf) {
        const unsigned short* A = SM + buf * 16384;
        const unsigned short* B = SM + 32768 + buf * 8192;
        #pragma unroll
        for (int kk = 0; kk < 2; ++kk) {
            int so = ((kk * 4 + quad) ^ (l16 & 7)) * 8;
            short8 a[4], b[4];
            #pragma unroll
            for (int m = 0; m < 4; ++m)
                a[m] = *(const short8*)&A[(wr * 64 + m * 16 + l16) * 64 + so];
            #pragma unroll
            for (int n = 0; n < 4; ++n)
                b[n] = *(const short8*)&B[(wc * 64 + n * 16 + l16) * 64 + so];
            #pragma unroll
            for (int m = 0; m < 4; ++m)
                #pragma unroll
                for (int n = 0; n < 4; ++n)
                    acc[m][n] = __builtin_amdgcn_mfma_f32_16x16x32_bf16(a[m], b[n], acc[m][n], 0, 0, 0);
        }
    };

    STAGE(0, 0);
    STAGE(1, 1);
    for (int kc = 0; kc < 8; ++kc) {
        if (kc < 7) { VMW(6); } else { VMW(0); }
        bar();
        COMPUTE(kc & 1);
        bar();
        if (kc + 2 < 8) STAGE(kc + 2, kc & 1);
    }

    // fused scales partial: sum over rows of y^2 per electron column
    float cs[4];
    #pragma unroll
    for (int n = 0; n < 4; ++n) {
        float s = 0.f;
        #pragma unroll
        for (int m = 0; m < 4; ++m)
            #pragma unroll
            for (int reg = 0; reg < 4; ++reg)
                s += acc[m][n][reg] * acc[m][n][reg];
        cs[n] = s;
    }
    #pragma unroll
    for (int n = 0; n < 4; ++n) {
        float s = cs[n];
        s += __shfl_xor(s, 16);
        s += __shfl_xor(s, 32);
        s += __shfl_xor(s, 1);
        s += __shfl_xor(s, 2);
        s += __shfl_xor(s, 4);
        if ((lane & 7) == 0 && lane < 16) {
            int n_elec = (N0 >> 3) + wc * 8 + n * 2 + (lane >> 3);
            atomicAdd(&s2[w * NE + n_elec], s);
        }
    }

    // epilogue: acc -> padded LDS bf16 tile (256 x 136) -> 16B stores
    unsigned short* T = SM;
    #pragma unroll
    for (int m = 0; m < 4; ++m)
        #pragma unroll
        for (int reg = 0; reg < 4; ++reg) {
            int row = wr * 64 + m * 16 + quad * 4 + reg;
            #pragma unroll
            for (int n = 0; n < 4; ++n)
                T[row * 136 + wc * 64 + n * 16 + l16] = f2bf(acc[m][n][reg]);
        }
    __syncthreads();
    #pragma unroll
    for (int i = 0; i < 8; ++i) {
        int c = t + 512 * i;
        int row = c & 255, cb = c >> 8;
        uint4 v = *(const uint4*)(T + row * 136 + cb * 8);
        int hl = M0 + row;
        unsigned short* dst = out + (size_t)(hl >> 6) * 1048576 + (size_t)(hl & 63) * 8
                                  + (size_t)((N0 >> 3) + cb) * 512;
        *(uint4*)dst = v;
    }
}

// ---------------------------------------------------------------------------
// K1.5: dT[h][f][n] = db[h][n][f] * rsqrt(s2d[n])
// ---------------------------------------------------------------------------
__global__ __launch_bounds__(256) void dtrans_kernel(
    const unsigned short* __restrict__ db, const float* __restrict__ s2d,
    unsigned short* __restrict__ dT)
{
    __shared__ float Ts[64 * 68];
    const int t = threadIdx.x;
    const int h = blockIdx.z, n0 = blockIdx.y * 64, f0 = blockIdx.x * 64;
    const int rr = t >> 3, cs = (t & 7) * 8;
    #pragma unroll
    for (int p = 0; p < 2; ++p) {
        int row = rr + p * 32;
        float sc = rsqrtf(s2d[n0 + row]);
        uint4 v = *(const uint4*)(db + ((size_t)h * NE + n0 + row) * 512 + f0 + cs);
        unsigned a[4] = {v.x, v.y, v.z, v.w};
        float* d = &Ts[row * 68 + cs];
        #pragma unroll
        for (int j = 0; j < 4; ++j) {
            d[2 * j]     = bf2f(a[j] & 0xffffu) * sc;
            d[2 * j + 1] = bf2f(a[j] >> 16) * sc;
        }
    }
    __syncthreads();
    const int f = t >> 2, ns = (t & 3) * 16;
    unsigned o[8];
    #pragma unroll
    for (int j = 0; j < 8; ++j)
        o[j] = pack2(Ts[(ns + 2 * j) * 68 + f], Ts[(ns + 2 * j + 1) * 68 + f]);
    unsigned short* dst = dT + ((size_t)h * 512 + f0 + f) * NE + n0 + ns;
    *(uint4*)dst       = make_uint4(o[0], o[1], o[2], o[3]);
    *(uint4*)(dst + 8) = make_uint4(o[4], o[5], o[6], o[7]);
}

// ---------------------------------------------------------------------------
// K2a: P[hg][n][m] = exp((q.k)*rsq(s2q[n])*rsq(s2k[m])) bf16.
// Frozen r10 structure; row-sum epilogue REMOVED (combine now computes the
// denominator via ones-MFMA). single-buffer 2-phase, (512,2), grid 512.
// ---------------------------------------------------------------------------
__global__ __launch_bounds__(512, 2) void score_kernel(
    const unsigned short* __restrict__ qb, const unsigned short* __restrict__ kb,
    const float* __restrict__ s2, unsigned short* __restrict__ P, int g)
{
    __shared__ unsigned short SM[34816];   // A[16384] | B[8192] staging; T[256*136] epilogue
    const int t = threadIdx.x;
    int bid = blockIdx.x + 16 * (blockIdx.y + 8 * blockIdx.z);
    int swz = (bid & 7) * 64 + (bid >> 3);
    const int bx = swz & 15, by = (swz >> 4) & 7, bz = swz >> 7;
    const int hg = bz, h = g * 4 + hg;
    const int n0 = by * 256, m0 = bx * 128;
    const int wave = t >> 6, lane = t & 63, quad = lane >> 4, l16 = lane & 15;
    const int wr = wave >> 1, wc = wave & 1;       // 4n x 2m wave grid
    const int lrow = lane >> 3;
    const int scol = ((lane & 7) ^ lrow) * 8;
    const unsigned short* qh = qb + (size_t)h * NE * 512;
    const unsigned short* kh = kb + (size_t)h * NE * 512;
    unsigned short* A = SM;
    unsigned short* B = SM + 16384;

    f32x4 acc[4][4];
    #pragma unroll
    for (int m = 0; m < 4; ++m)
        #pragma unroll
        for (int n = 0; n < 4; ++n) acc[m][n] = {0.f, 0.f, 0.f, 0.f};

    for (int kc = 0; kc < 8; ++kc) {
        #pragma unroll
        for (int p = 0; p < 4; ++p) {
            int c = p * 8 + wave;
            gld16(A + c * 512, qh + (size_t)(n0 + c * 8 + lrow) * 512 + kc * 64 + scol);
        }
        #pragma unroll
        for (int p = 0; p < 2; ++p) {
            int c = p * 8 + wave;
            gld16(B + c * 512, kh + (size_t)(m0 + c * 8 + lrow) * 512 + kc * 64 + scol);
        }
        __syncthreads();
        #pragma unroll
        for (int kk = 0; kk < 2; ++kk) {
            int so = ((kk * 4 + quad) ^ (l16 & 7)) * 8;
            short8 a[4], b[4];
            #pragma unroll
            for (int m = 0; m < 4; ++m)
                a[m] = *(const short8*)&A[(wr * 64 + m * 16 + l16) * 64 + so];
            #pragma unroll
            for (int n = 0; n < 4; ++n)
                b[n] = *(const short8*)&B[(wc * 64 + n * 16 + l16) * 64 + so];
            #pragma unroll
            for (int m = 0; m < 4; ++m)
                #pragma unroll
                for (int n = 0; n < 4; ++n)
                    acc[m][n] = __builtin_amdgcn_mfma_f32_16x16x32_bf16(a[m], b[n], acc[m][n], 0, 0, 0);
        }
        __syncthreads();
    }

    float ik[4];
    #pragma unroll
    for (int n = 0; n < 4; ++n) ik[n] = rsqrtf(s2[NE + m0 + wc * 64 + n * 16 + l16]);

    unsigned short* T = SM;                        // 256*136 shorts = 69.6 KB
    #pragma unroll
    for (int m = 0; m < 4; ++m)
        #pragma unroll
        for (int reg = 0; reg < 4; ++reg) {
            int row = wr * 64 + m * 16 + quad * 4 + reg;
            float qs = rsqrtf(s2[n0 + row]);
            #pragma unroll
            for (int n = 0; n < 4; ++n) {
                float e = __expf(acc[m][n][reg] * qs * ik[n]);
                T[row * 136 + wc * 64 + n * 16 + l16] = f2bf(e);
            }
        }
    __syncthreads();
    unsigned short* Ph = P + (size_t)hg * NE * NE;
    #pragma unroll
    for (int i = 0; i < 8; ++i) {
        int c = t + 512 * i;
        int row = c >> 4, cb = c & 15;
        uint4 v = *(const uint4*)(T + row * 136 + cb * 8);
        *(uint4*)(Ph + (size_t)(n0 + row) * NE + m0 + cb * 8) = v;
    }
}

// ---------------------------------------------------------------------------
// K2b: V[n][f] = (sum_m P[n][m]*dT[f][m]) / (sum_m P[n][m])
// Frozen r9 pipeline; NEW: denominator via ones-vector MFMA (P . 1) — exact
// same bf16 P values as the numerator, no sums buffer/atomics needed.
// BK=128, 512 thr, 128n x 128f, counted-vmcnt(8) 2-deep dbuf (128 KB LDS).
// ---------------------------------------------------------------------------
__global__ __launch_bounds__(512, 1) void combine_kernel(
    const unsigned short* __restrict__ P, const unsigned short* __restrict__ dT,
    float* __restrict__ out, int g)
{
    __shared__ unsigned short Ps[2][16384];
    __shared__ unsigned short Ds[2][16384];
    const int t = threadIdx.x;
    int bid = blockIdx.x + 4 * (blockIdx.y + 16 * blockIdx.z);
    int swz = (bid & 7) * 32 + (bid >> 3);
    const int bx = swz & 3, by = (swz >> 2) & 15, bz = swz >> 6;
    const int hg = bz, h = g * 4 + hg;
    const int n0 = by * 128, f0 = bx * 128;
    const int wave = t >> 6, lane = t & 63, quad = lane >> 4, l16 = lane & 15;
    const int wn = wave >> 1, wf = wave & 1;
    const int lrow4 = lane >> 4;
    const unsigned short* Ph = P + (size_t)hg * NE * NE;
    const unsigned short* dh = dT + (size_t)h * 512 * NE;

    f32x4 acc[2][4];
    #pragma unroll
    for (int i = 0; i < 2; ++i)
        #pragma unroll
        for (int j = 0; j < 4; ++j) acc[i][j] = {0.f, 0.f, 0.f, 0.f};
    f32x4 accs[2] = {{0.f, 0.f, 0.f, 0.f}, {0.f, 0.f, 0.f, 0.f}};
    short8 ones;
    #pragma unroll
    for (int j = 0; j < 8; ++j) ones[j] = (short)0x3F80;   // bf16 1.0

    auto STAGE = [&](int mc, int buf) {
        #pragma unroll
        for (int p = 0; p < 4; ++p) {
            int c = p * 8 + wave;
            int row = c * 4 + lrow4;
            int sb = ((lane & 15) ^ (row & 15)) * 8;
            gld16(&Ps[buf][c * 512], Ph + (size_t)(n0 + row) * NE + mc * 128 + sb);
        }
        #pragma unroll
        for (int p = 0; p < 4; ++p) {
            int c = p * 8 + wave;
            int row = c * 4 + lrow4;
            int sb = ((lane & 15) ^ (row & 15)) * 8;
            gld16(&Ds[buf][c * 512], dh + (size_t)(f0 + row) * NE + mc * 128 + sb);
        }
    };
    auto COMPUTE = [&](int buf) {
        #pragma unroll
        for (int kk = 0; kk < 4; ++kk) {
            int so = ((kk * 4 + quad) ^ l16) * 8;
            short8 a0 = *(const short8*)&Ps[buf][(wn * 32 + l16) * 128 + so];
            short8 a1 = *(const short8*)&Ps[buf][(wn * 32 + 16 + l16) * 128 + so];
            accs[0] = __builtin_amdgcn_mfma_f32_16x16x32_bf16(a0, ones, accs[0], 0, 0, 0);
            accs[1] = __builtin_amdgcn_mfma_f32_16x16x32_bf16(a1, ones, accs[1], 0, 0, 0);
            #pragma unroll
            for (int ct = 0; ct < 4; ++ct) {
                short8 bb = *(const short8*)&Ds[buf][(wf * 64 + ct * 16 + l16) * 128 + so];
                acc[0][ct] = __builtin_amdgcn_mfma_f32_16x16x32_bf16(a0, bb, acc[0][ct], 0, 0, 0);
                acc[1][ct] = __builtin_amdgcn_mfma_f32_16x16x32_bf16(a1, bb, acc[1][ct], 0, 0, 0);
            }
        }
    };

    STAGE(0, 0);
    STAGE(1, 1);
    for (int mc = 0; mc < 16; ++mc) {
        if (mc < 15) { VMW(8); } else { VMW(0); }
        bar();
        COMPUTE(mc & 1);
        bar();
        if (mc + 2 < 16) STAGE(mc + 2, mc & 1);
    }

    #pragma unroll
    for (int rt = 0; rt < 2; ++rt)
        #pragma unroll
        for (int reg = 0; reg < 4; ++reg) {
            int nl = wn * 32 + rt * 16 + quad * 4 + reg;
            float li = 1.0f / accs[rt][reg];
            float* orow = out + (size_t)(n0 + nl) * 4096 + h * 512 + f0 + wf * 64;
            #pragma unroll
            for (int ct = 0; ct < 4; ++ct)
                orow[ct * 16 + l16] = acc[rt][ct][reg] * li;
        }
}

extern "C" void kernel_launch(void* const* d_in, const int* in_sizes, int n_in,
                              void* d_out, int out_size, void* d_ws, size_t ws_size,
                              hipStream_t stream)
{
    const float* x  = (const float*)d_in[0];
    const float* Qw = (const float*)d_in[1];
    const float* Kw = (const float*)d_in[2];
    const float* Dw = (const float*)d_in[3];
    float* out = (float*)d_out;

    char* ws = (char*)d_ws;
    unsigned short* xt = (unsigned short*)ws;                          // 16 MB
    unsigned short* db = (unsigned short*)(ws + 16777216);             // 16 MB
    unsigned short* P  = (unsigned short*)ws;                          // 32 MB (reuse)
    unsigned short* qb = (unsigned short*)(ws + 33554432);             // 16 MB
    unsigned short* kb = (unsigned short*)(ws + 33554432 + 16777216);  // 16 MB
    unsigned short* dT = (unsigned short*)(ws + 33554432 + 2 * 16777216); // 16 MB
    unsigned short* wbf = dT;                                          // 1.5 MB (reuse)
    float* s2     = (float*)(ws + 83886080);                           // 24 KB

    hipMemsetAsync(s2, 0, 3 * NE * sizeof(float), stream);
    prep_kernel<<<2432, 256, 0, stream>>>(x, Qw, Kw, Dw, xt, wbf);
    proj_gemm<<<dim3(128, 2, 3), 512, 0, stream>>>(wbf, xt, qb, kb, db, s2);
    dtrans_kernel<<<dim3(8, 32, 8), 256, 0, stream>>>(db, s2 + 2 * NE, dT);
    for (int g = 0; g < 2; ++g) {
        score_kernel<<<dim3(16, 8, 4), 512, 0, stream>>>(qb, kb, s2, P, g);
        combine_kernel<<<dim3(4, 16, 4), 512, 0, stream>>>(P, dT, out, g);
    }
}